// Round 8
// baseline (459.139 us; speedup 1.0000x reference)
//
#include <hip/hip_runtime.h>

// ---------------------------------------------------------------------------
// VARS_D: fused linear-attention block on gfx950. Round 12.
//  - qkv + proj: shared 128x256-tile BK=32 core, acc 4x4 (64 VGPR) + 48KB LDS
//    + __launch_bounds__(512,4) -> 2 blocks/CU (was 252 regs + 128KB -> 1
//    block, 2 waves/SIMD, no inter-block hiding: the real cause of the
//    26-37% MfmaUtil plateau across r6/r7/r9 schedules). Counted vmcnt(3)
//    pipeline; swizzle = proven gemm_core_nt pattern.
//  - rf, kkkv, k_red, ista2, attn unchanged from r11 (best measured).
// ---------------------------------------------------------------------------

typedef __attribute__((ext_vector_type(8))) short bf16x8;
typedef __attribute__((ext_vector_type(4))) float f32x4;

#define GLD16(gptr, lptr)                                                              \
  __builtin_amdgcn_global_load_lds((const __attribute__((address_space(1))) void*)(gptr), \
                                   (__attribute__((address_space(3))) void*)(lptr), 16, 0, 0)

__device__ __forceinline__ unsigned short f2bf(float f) {
  union { float f; unsigned int u; } v; v.f = f;
  unsigned int r = v.u + 0x7fffu + ((v.u >> 16) & 1u);   // RNE
  return (unsigned short)(r >> 16);
}
__device__ __forceinline__ float bf2f(unsigned short s) {
  union { unsigned int u; float f; } v; v.u = ((unsigned int)s) << 16;
  return v.f;
}
__device__ __forceinline__ float rn_of(float css) {
  return 1.f / fmaxf(sqrtf(css), 1e-12f);
}

// ---------------------------------------------------------------------------
// 128x256 NT GEMM core, BK=32, 512 threads / 8 waves (2M x 4N, 64x64/wave),
// 2x 24KB LDS buffers. Designed for 2 blocks/CU (<=128 regs incl. acc).
// Per tile t: {8 ds_read_b128 -> lgkm(0) -> 16 MFMA -> barrier ->
//              stage(t+2) -> vmcnt(3) [waits tile t+1; t+2 in flight] -> barrier}.
// WAR: the first barrier joins all waves past their reads of buf b before
// stage(t+2) overwrites it. Chunk swizzle = gemm_core_nt pattern (proven):
// physical k-chunk p of row R holds logical chunk p ^ ((R>>1)&3); reader at
// logical quad uses physical (quad ^ ((l16>>1)&3)).
// ---------------------------------------------------------------------------
template<int NT>
__device__ __forceinline__ void gemm_bk32_core(
    const unsigned short* __restrict__ A,   // 128 rows x ldk
    const unsigned short* __restrict__ B,   // 256 rows x ldk
    int ldk,
    f32x4 (&acc)[4][4],
    unsigned short* smem) {
  const int tid = threadIdx.x;
  const int lane = tid & 63, wave = tid >> 6;
  const int l16 = lane & 15, quad = lane >> 4;
  const int wr = wave >> 2, wc = wave & 3;
  const int fsw = (l16 >> 1) & 3;

#pragma unroll
  for (int m = 0; m < 4; m++)
#pragma unroll
    for (int n = 0; n < 4; n++)
#pragma unroll
      for (int r = 0; r < 4; r++) acc[m][n][r] = 0.f;

  const int arow = tid >> 2;                                 // 0..127
  const int asw = (((tid & 3) ^ ((arow >> 1) & 3)) << 3);    // swizzled k-off (elems)
  const int dstw = wave * 512;                               // wave-uniform LDS base

  auto stage = [&](int T) {  // 3 GLD/thread: A(1) + B(2)
    unsigned short* d = smem + (T & 1) * 12288;
    GLD16(A + (long)arow * ldk + T * 32 + asw, d + dstw);
    GLD16(B + (long)arow * ldk + T * 32 + asw, d + 4096 + dstw);
    GLD16(B + (long)(arow + 128) * ldk + T * 32 + asw, d + 8192 + dstw);
  };

  bf16x8 af[4], bn[4];
  auto rdAB = [&](int b) {  // 8 x ds_read_b128
    const unsigned short* Ab = smem + b * 12288;
    const unsigned short* Bb = Ab + 4096;
#pragma unroll
    for (int m = 0; m < 4; m++)
      af[m] = *(const bf16x8*)(Ab + (wr * 64 + m * 16 + l16) * 32 + ((quad ^ fsw) << 3));
#pragma unroll
    for (int n = 0; n < 4; n++)
      bn[n] = *(const bf16x8*)(Bb + (wc * 64 + n * 16 + l16) * 32 + ((quad ^ fsw) << 3));
  };

#define FENCE asm volatile("" ::: "memory")
#define SGB __builtin_amdgcn_sched_barrier(0)

  stage(0); stage(1);
  asm volatile("s_waitcnt vmcnt(3)" ::: "memory");  // tile0 landed; tile1 in flight
  __builtin_amdgcn_s_barrier();

#pragma unroll 1
  for (int t = 0; t < NT; t++) {
    const int b = t & 1;
    rdAB(b);
    asm volatile("s_waitcnt lgkmcnt(0)" ::: "memory"); SGB;
    __builtin_amdgcn_s_setprio(1);
#pragma unroll
    for (int m = 0; m < 4; m++)
#pragma unroll
      for (int n = 0; n < 4; n++)
        acc[m][n] = __builtin_amdgcn_mfma_f32_16x16x32_bf16(af[m], bn[n], acc[m][n], 0, 0, 0);
    __builtin_amdgcn_s_setprio(0);
    FENCE; __builtin_amdgcn_s_barrier();        // all waves done reading buf b
    if (t + 2 < NT) stage(t + 2);               // overwrite buf b (WAR-safe)
    if (t + 1 < NT) {
      if (t + 2 < NT) { asm volatile("s_waitcnt vmcnt(3)" ::: "memory"); }
      else            { asm volatile("s_waitcnt vmcnt(0)" ::: "memory"); }
      FENCE; __builtin_amdgcn_s_barrier();      // tile t+1 visible to all waves
    }
  }
#undef FENCE
#undef SGB
}

// ---------------- convert: fp32 -> bf16 ----------------
__global__ __launch_bounds__(256) void k_convert_bf16(const float* __restrict__ in,
                                                      unsigned short* __restrict__ out, long n4) {
  long i = (long)blockIdx.x * 256 + threadIdx.x;
  if (i < n4) {
    float4 v = ((const float4*)in)[i];
    unsigned short o[4] = {f2bf(v.x), f2bf(v.y), f2bf(v.z), f2bf(v.w)};
    ((uint2*)out)[i] = *(uint2*)o;
  }
}

// ---------------- T: tiled batched transpose fp32[R,C] -> bf16[C,R] ----------------
__global__ __launch_bounds__(256) void k_transpose_tiled(const float* __restrict__ in,
                                                         unsigned short* __restrict__ out,
                                                         int R, int C, float scale) {
  __shared__ float t[32][33];
  const float* ib = in + (long)blockIdx.z * R * C;
  unsigned short* ob = out + (long)blockIdx.z * R * C;
  int c0 = blockIdx.x * 32, r0 = blockIdx.y * 32;
  int tx = threadIdx.x & 31, ty = threadIdx.x >> 5;
#pragma unroll
  for (int k = 0; k < 32; k += 8)
    t[ty + k][tx] = ib[(long)(r0 + ty + k) * C + c0 + tx];
  __syncthreads();
#pragma unroll
  for (int k = 0; k < 32; k += 8)
    ob[(long)(c0 + ty + k) * R + r0 + tx] = f2bf(t[tx][ty + k] * scale);
}

// ---------------- K1: qkv GEMM, 128x256 BK32 core (1536 blocks, 2/CU) ----------------
__global__ __launch_bounds__(512, 4) void k_gemm_qkv128(const unsigned short* __restrict__ xbf,
                                                        const unsigned short* __restrict__ wqkvT,
                                                        unsigned short* __restrict__ q,
                                                        unsigned short* __restrict__ vT) {
  __shared__ __align__(16) unsigned short smem[24576];  // 48KB core; v-pool reuses (36KB)
  f32x4 acc[4][4];
  const int L = blockIdx.x;
  const int xcd = L & 7, slot = L >> 3;          // 192 slots per XCD
  const int rt = xcd * 32 + slot / 6;            // 256 row-tiles of 128
  const int ct = slot % 6;
  gemm_bk32_core<24>(xbf + (long)rt * 128 * 768, wqkvT + (long)ct * 256 * 768, 768, acc, smem);

  const int tid = threadIdx.x, lane = tid & 63, wave = tid >> 6;
  const int l16 = lane & 15, quad = lane >> 4;
  const int wr = wave >> 2, wc = wave & 3;
  const int b = rt >> 5;                          // 32 row-tiles per batch
  const int nbase = (rt & 31) * 128;
  if (ct < 3) {  // pure-q columns -> q[bh][n][d]
#pragma unroll
    for (int m = 0; m < 4; m++)
#pragma unroll
      for (int n = 0; n < 4; n++) {
        int col = ct * 256 + wc * 64 + n * 16 + l16;
        int h = col >> 6, d = col & 63;
#pragma unroll
        for (int r = 0; r < 4; r++) {
          int nr = nbase + wr * 64 + m * 16 + quad * 4 + r;
          q[((long)(b * 12 + h) * 4096 + nr) * 64 + d] = f2bf(acc[m][n][r]);
        }
      }
  } else {  // pure-v columns: LDS transpose -> vT[bh][d][n]
    unsigned short* pool = smem;  // [col 256][nloc 64 + 8 pad] = 36KB
    for (int hh = 0; hh < 2; hh++) {
      __syncthreads();
      if (wr == hh) {
#pragma unroll
        for (int m = 0; m < 4; m++)
#pragma unroll
          for (int n = 0; n < 4; n++)
#pragma unroll
            for (int r = 0; r < 4; r++)
              pool[(wc * 64 + n * 16 + l16) * 72 + m * 16 + quad * 4 + r] = f2bf(acc[m][n][r]);
      }
      __syncthreads();
#pragma unroll
      for (int c = 0; c < 4; c++) {  // 2048 uint4 chunks = 256 cols x 8
        int chunk = c * 512 + tid;
        int col = chunk >> 3, ng = chunk & 7;
        uint4 val = *(const uint4*)&pool[col * 72 + ng * 8];
        int vcol = (ct - 3) * 256 + col;
        int h = vcol >> 6, d = vcol & 63;
        long n = nbase + hh * 64 + ng * 8;
        *(uint4*)&vT[((long)(b * 12 + h) * 64 + d) * 4096 + n] = val;
      }
    }
  }
}

// ---------------- K3: rf GEMM, full-tile staged, halfnorm folded ----------------
__global__ __launch_bounds__(256) void k_gemm_rf(const unsigned short* __restrict__ q,
                                                 const unsigned short* __restrict__ rmT,
                                                 unsigned short* __restrict__ qnT,
                                                 float* __restrict__ colss) {
  __shared__ __align__(16) unsigned short smem[16384];
  __shared__ float hnp[256];
  __shared__ float css[128];
  unsigned short* Asm = smem;
  unsigned short* Bsm = smem + 8192;
  unsigned short* pool = smem;
  f32x4 acc[4][4];
  const int nt = blockIdx.x, bh = blockIdx.y, h = bh % 12;
  const int tid = threadIdx.x, lane = tid & 63, wave = tid >> 6;
  const int l16 = lane & 15, quad = lane >> 4;
  const int wm = (wave >> 1) * 64, wn = (wave & 1) * 64;
  const int fsw = (l16 >> 1) & 3;
  const unsigned short* Aq = q + ((long)bh * 4096 + nt * 128) * 64;
  const unsigned short* Brm = rmT + (long)h * 8192;

#pragma unroll
  for (int c = 0; c < 4; c++) {
    int chunk = c * 256 + tid;
    int row = chunk >> 3, ko8 = chunk & 7;
    int kc = ko8 >> 2;
    int c2s = (ko8 & 3) ^ ((row >> 1) & 3);
    *(uint4*)(Asm + kc * 4096 + row * 32 + c2s * 8) = *(const uint4*)(Aq + (long)row * 64 + ko8 * 8);
    *(uint4*)(Bsm + kc * 4096 + row * 32 + c2s * 8) = *(const uint4*)(Brm + (long)row * 64 + ko8 * 8);
  }
  for (int i = tid; i < 128; i += 256) css[i] = 0.f;
  __syncthreads();
  {
    const unsigned short* ap = Asm + (tid & 1) * 4096 + (tid >> 1) * 32;
    float ssum = 0.f;
#pragma unroll
    for (int e = 0; e < 32; e++) { float f = bf2f(ap[e]); ssum += f * f; }
    hnp[tid] = ssum;
  }
#pragma unroll
  for (int i = 0; i < 4; i++)
#pragma unroll
    for (int j = 0; j < 4; j++)
#pragma unroll
      for (int r = 0; r < 4; r++) acc[i][j][r] = 0.f;
#pragma unroll
  for (int kc = 0; kc < 2; kc++) {
    bf16x8 af[4], bfr[4];
#pragma unroll
    for (int i = 0; i < 4; i++)
      af[i] = *(const bf16x8*)(Asm + kc * 4096 + (wm + i * 16 + l16) * 32 + ((quad ^ fsw) * 8));
#pragma unroll
    for (int j = 0; j < 4; j++)
      bfr[j] = *(const bf16x8*)(Bsm + kc * 4096 + (wn + j * 16 + l16) * 32 + ((quad ^ fsw) * 8));
#pragma unroll
    for (int i = 0; i < 4; i++)
#pragma unroll
      for (int j = 0; j < 4; j++)
        acc[i][j] = __builtin_amdgcn_mfma_f32_16x16x32_bf16(af[i], bfr[j], acc[i][j], 0, 0, 0);
  }
  __syncthreads();
  float hnv[4][4];
#pragma unroll
  for (int i = 0; i < 4; i++)
#pragma unroll
    for (int r = 0; r < 4; r++) {
      int row = wm + i * 16 + quad * 4 + r;
      hnv[i][r] = 0.0625f * (hnp[2 * row] + hnp[2 * row + 1]);
    }
#pragma unroll
  for (int j = 0; j < 4; j++) {
    int col = wn + j * 16 + l16;
    float cp = 0.f;
#pragma unroll
    for (int i = 0; i < 4; i++)
#pragma unroll
      for (int r = 0; r < 4; r++) {
        float v = __expf(acc[i][j][r] - hnv[i][r]) * 0.08838834764831845f;
        acc[i][j][r] = v;
        cp += v * v;
      }
    atomicAdd(&css[col], cp);
  }
  __syncthreads();
  for (int i = tid; i < 128; i += 256) atomicAdd(&colss[bh * 128 + i], css[i]);
  for (int hh = 0; hh < 2; hh++) {
    __syncthreads();
    if ((wave >> 1) == hh) {
#pragma unroll
      for (int i = 0; i < 4; i++)
#pragma unroll
        for (int j = 0; j < 4; j++)
#pragma unroll
          for (int r = 0; r < 4; r++)
            pool[(i * 16 + quad * 4 + r) * 134 + wn + j * 16 + l16] = f2bf(acc[i][j][r]);
    }
    __syncthreads();
#pragma unroll
    for (int c = 0; c < 4; c++) {
      int chunk = tid + c * 256;
      int m = chunk >> 3, nj = (chunk & 7) * 8;
      unsigned short o[8];
#pragma unroll
      for (int e = 0; e < 8; e++) o[e] = pool[(nj + e) * 134 + m];
      *(uint4*)&qnT[((long)bh * 128 + m) * 4096 + nt * 128 + hh * 64 + nj] = *(uint4*)o;
    }
  }
}

// ---------------- K5: kk|kv NT GEMM, A-panel shared for B0 ----------------
__global__ __launch_bounds__(256) void k_gemm_kkkv(const unsigned short* __restrict__ qnT,
                                                   const unsigned short* __restrict__ vT,
                                                   const float* __restrict__ colss,
                                                   unsigned short* __restrict__ kkp) {
  __shared__ __align__(16) unsigned short As[128 * 32], Bs[64 * 32];
  f32x4 acc[4][6];
  const int ks = blockIdx.x, bh = blockIdx.y;
  const unsigned short* A = qnT + (long)bh * 128 * 4096 + ks * 512;
  const unsigned short* B1 = vT + (long)bh * 64 * 4096 + ks * 512;
  const int tid = threadIdx.x, lane = tid & 63, wave = tid >> 6;
  const int l16 = lane & 15, quad = lane >> 4;
  const int wm = (wave >> 1) * 64, wn = (wave & 1) * 96;
  const int arow = tid >> 2;
  const int akos = (((tid & 3) ^ ((arow >> 1) & 3)) << 3);
  const int fsw = (l16 >> 1) & 3;
#pragma unroll
  for (int i = 0; i < 4; i++)
#pragma unroll
    for (int j = 0; j < 6; j++)
#pragma unroll
      for (int r = 0; r < 4; r++) acc[i][j][r] = 0.f;
  for (int k0 = 0; k0 < 512; k0 += 32) {
    __syncthreads();
    GLD16(A + (long)arow * 4096 + k0 + akos, As + wave * 512);
    GLD16(A + (long)(arow + 64) * 4096 + k0 + akos, As + 2048 + wave * 512);
    GLD16(B1 + (long)arow * 4096 + k0 + akos, Bs + wave * 512);
    __syncthreads();
    bf16x8 af[4], bfr[6];
#pragma unroll
    for (int i = 0; i < 4; i++)
      af[i] = *(const bf16x8*)(As + (wm + i * 16 + l16) * 32 + ((quad ^ fsw) * 8));
#pragma unroll
    for (int j = 0; j < 6; j++) {
      int row = wn + j * 16 + l16;
      const unsigned short* rp = (row < 128) ? (As + row * 32) : (Bs + (row - 128) * 32);
      bfr[j] = *(const bf16x8*)(rp + ((quad ^ fsw) * 8));
    }
#pragma unroll
    for (int i = 0; i < 4; i++)
#pragma unroll
      for (int j = 0; j < 6; j++)
        acc[i][j] = __builtin_amdgcn_mfma_f32_16x16x32_bf16(af[i], bfr[j], acc[i][j], 0, 0, 0);
  }
  unsigned short* dst = kkp + ((long)ks * 96 + bh) * 24576;
  float rnr[4][4];
#pragma unroll
  for (int i = 0; i < 4; i++)
#pragma unroll
    for (int r = 0; r < 4; r++)
      rnr[i][r] = rn_of(colss[bh * 128 + wm + i * 16 + quad * 4 + r]);
#pragma unroll
  for (int j = 0; j < 6; j++) {
    int col = wn + j * 16 + l16;
    float rnc = (col < 128) ? rn_of(colss[bh * 128 + col]) : 1.f;
#pragma unroll
    for (int i = 0; i < 4; i++)
#pragma unroll
      for (int r = 0; r < 4; r++) {
        int row = wm + i * 16 + quad * 4 + r;
        dst[row * 192 + col] = f2bf(acc[i][j][r] * rnr[i][r] * rnc);
      }
  }
}

// ---------------- K5b: reduce kkp 8 K-partials (full-chip width) ----------------
__global__ __launch_bounds__(256) void k_red(const unsigned short* __restrict__ kkp,
                                             unsigned short* __restrict__ kkred,
                                             float* __restrict__ kvred) {
  const int g = blockIdx.x, bh = blockIdx.y;
  const int tid = threadIdx.x;
  const unsigned short* base = kkp + (long)bh * 24576 + (long)(g * 32) * 192;
#pragma unroll
  for (int c = 0; c < 3; c++) {
    int idx = c * 256 + tid;
    int m = idx / 24, c8 = idx % 24;
    float f[8] = {0.f, 0.f, 0.f, 0.f, 0.f, 0.f, 0.f, 0.f};
#pragma unroll
    for (int ks = 0; ks < 8; ks++) {
      union { uint4 u; unsigned short s[8]; } u;
      u.u = *(const uint4*)(base + (long)ks * 2359296 + m * 192 + c8 * 8);
#pragma unroll
      for (int e = 0; e < 8; e++) f[e] += bf2f(u.s[e]);
    }
    long row = (long)bh * 128 + g * 32 + m;
    if (c8 < 16) {
      unsigned short o[8];
#pragma unroll
      for (int e = 0; e < 8; e++) o[e] = f2bf(f[e]);
      *(uint4*)&kkred[row * 128 + c8 * 8] = *(uint4*)o;
    } else {
      *(float4*)&kvred[row * 64 + (c8 - 16) * 8] = make_float4(f[0], f[1], f[2], f[3]);
      *(float4*)&kvred[row * 64 + (c8 - 16) * 8 + 4] = make_float4(f[4], f[5], f[6], f[7]);
    }
  }
}

// ---------------- K6: ISTA via MFMA (loads pre-reduced kk/kv) ----------------
__global__ __launch_bounds__(256) void k_ista2(const unsigned short* __restrict__ kkred,
                                               const float* __restrict__ kvred,
                                               const float* __restrict__ colss,
                                               unsigned short* __restrict__ sT) {
  __shared__ __align__(16) unsigned short kks[128 * 144];
  __shared__ __align__(16) unsigned short ssT[64 * 144];
  __shared__ float kvs[128 * 64];
  __shared__ float red[128];
  __shared__ float rns[128];
  const int tid = threadIdx.x, lane = tid & 63, wave = tid >> 6;
  const int l16 = lane & 15, quad = lane >> 4;
  const int wm = (wave >> 1) * 64, wn = (wave & 1) * 32;
  const int bh = blockIdx.x;
  for (int idx = tid; idx < 2048; idx += 256) {
    int m = idx >> 4, c8 = idx & 15;
    uint4 v = *(const uint4*)(kkred + ((long)bh * 128 + m) * 128 + c8 * 8);
    *(uint4*)&kks[m * 144 + c8 * 8] = v;
  }
  for (int idx = tid; idx < 2048; idx += 256) {
    int m = idx >> 4, c4 = idx & 15;
    float4 v = *(const float4*)(kvred + ((long)bh * 128 + m) * 64 + c4 * 4);
    *(float4*)&kvs[m * 64 + c4 * 4] = v;
  }
  __syncthreads();
  float kv[4][2][4];
#pragma unroll
  for (int i = 0; i < 4; i++)
#pragma unroll
    for (int j = 0; j < 2; j++)
#pragma unroll
      for (int r = 0; r < 4; r++) {
        int m = wm + i * 16 + quad * 4 + r, d = wn + j * 16 + l16;
        kv[i][j][r] = kvs[m * 64 + d];
      }
  if (tid < 128) {
    float rs = 0.f;
    const unsigned short* rp = kks + tid * 144;
    for (int p = 0; p < 128; p++) rs += fabsf(bf2f(rp[p]));
    red[tid] = rs;
    rns[tid] = rn_of(colss[bh * 128 + tid]);
  }
  __syncthreads();
  for (int o = 64; o > 0; o >>= 1) {
    if (tid < o) red[tid] = fmaxf(red[tid], red[tid + o]);
    __syncthreads();
  }
  const float L = red[0] + 1.f;
  const float invL = 1.f / L;
  const float lamL = 0.3f * invL;
  float sreg[4][2][4];
#pragma unroll
  for (int i = 0; i < 4; i++)
#pragma unroll
    for (int j = 0; j < 2; j++)
#pragma unroll
      for (int r = 0; r < 4; r++) {
        float z = kv[i][j][r];
        float az = fabsf(z) - 0.3f;
        float s = az > 0.f ? copysignf(az, z) : 0.f;
        sreg[i][j][r] = s;
        ssT[(wn + j * 16 + l16) * 144 + wm + i * 16 + quad * 4 + r] = f2bf(s);
      }
  for (int step = 0; step < 5; step++) {
    __syncthreads();
    f32x4 acc[4][2];
#pragma unroll
    for (int i = 0; i < 4; i++)
#pragma unroll
      for (int j = 0; j < 2; j++)
#pragma unroll
        for (int r = 0; r < 4; r++) acc[i][j][r] = 0.f;
#pragma unroll
    for (int kc = 0; kc < 4; kc++) {
      bf16x8 af[4], bfj[2];
#pragma unroll
      for (int i = 0; i < 4; i++)
        af[i] = *(const bf16x8*)(kks + (wm + i * 16 + l16) * 144 + kc * 32 + quad * 8);
#pragma unroll
      for (int j = 0; j < 2; j++)
        bfj[j] = *(const bf16x8*)(ssT + (wn + j * 16 + l16) * 144 + kc * 32 + quad * 8);
#pragma unroll
      for (int i = 0; i < 4; i++)
#pragma unroll
        for (int j = 0; j < 2; j++)
          acc[i][j] = __builtin_amdgcn_mfma_f32_16x16x32_bf16(af[i], bfj[j], acc[i][j], 0, 0, 0);
    }
    __syncthreads();
#pragma unroll
    for (int i = 0; i < 4; i++)
#pragma unroll
      for (int j = 0; j < 2; j++)
#pragma unroll
        for (int r = 0; r < 4; r++) {
          float z = sreg[i][j][r] - (acc[i][j][r] - kv[i][j][r]) * invL;
          float az = fabsf(z) - lamL;
          float s = az > 0.f ? copysignf(az, z) : 0.f;
          sreg[i][j][r] = s;
          ssT[(wn + j * 16 + l16) * 144 + wm + i * 16 + quad * 4 + r] = f2bf(s);
        }
  }
#pragma unroll
  for (int i = 0; i < 4; i++)
#pragma unroll
    for (int j = 0; j < 2; j++)
#pragma unroll
      for (int r = 0; r < 4; r++) {
        int m = wm + i * 16 + quad * 4 + r, d = wn + j * 16 + l16;
        sT[(long)bh * 8192 + d * 128 + m] = f2bf(sreg[i][j][r] * rns[m]);
      }
}

// ---------------- K7: attn = qn @ s; permuted As2 (conflict-free gather) ----------------
__global__ __launch_bounds__(256) void k_gemm_attn(const unsigned short* __restrict__ qnT,
                                                   const unsigned short* __restrict__ sT,
                                                   unsigned short* __restrict__ attn) {
  __shared__ __align__(16) unsigned short As2[4352];
  __shared__ __align__(16) unsigned short Bs[64 * 32];
  f32x4 acc[4][2];
  const int nt = blockIdx.x, bh = blockIdx.y;
  const int b = bh / 12, h = bh % 12;
  const int tid = threadIdx.x, lane = tid & 63, wave = tid >> 6;
  const int l16 = lane & 15, quad = lane >> 4;
  const int wm = (wave >> 1) * 64, wn = (wave & 1) * 32;
  const int fsw = (l16 >> 1) & 3;
#pragma unroll
  for (int i = 0; i < 4; i++)
#pragma unroll
    for (int j = 0; j < 2; j++)
#pragma unroll
      for (int r = 0; r < 4; r++) acc[i][j][r] = 0.f;
  for (int k0 = 0; k0 < 128; k0 += 32) {
    __syncthreads();
#pragma unroll
    for (int it = 0; it < 3; it++) {
      if (it < 2 || tid < 32) {
        int c = it * 256 + tid;
        int p = (c * 241) >> 12;
        int nh = c - p * 17;
        int k = ((p & 7) << 2) + (p >> 3);
        int n8 = (nh < 16 ? nh : 15) << 3;
        const unsigned short* gp = qnT + ((long)bh * 128 + k0 + k) * 4096 + nt * 128 + n8;
        GLD16(gp, As2 + (it * 256 + wave * 64) * 8);
      }
    }
    {
      int dd = tid >> 2;
      int ko = (((tid & 3) ^ ((dd >> 1) & 3)) * 8);
      const unsigned short* gp = sT + ((long)bh * 64 + dd) * 128 + k0 + ko;
      GLD16(gp, Bs + wave * 512);
    }
    __syncthreads();
    bf16x8 af[4], bfr[2];
#pragma unroll
    for (int i = 0; i < 4; i++) {
      union { bf16x8 v; unsigned short s[8]; } u;
#pragma unroll
      for (int e = 0; e < 8; e++) {
        int p = ((e & 3) << 3) + (quad << 1) + (e >> 2);
        u.s[e] = As2[p * 136 + wm + i * 16 + l16];
      }
      af[i] = u.v;
    }
#pragma unroll
    for (int j = 0; j < 2; j++)
      bfr[j] = *(const bf16x8*)&Bs[(wn + j * 16 + l16) * 32 + ((quad ^ fsw) * 8)];
#pragma unroll
    for (int i = 0; i < 4; i++)
#pragma unroll
      for (int j = 0; j < 2; j++)
        acc[i][j] = __builtin_amdgcn_mfma_f32_16x16x32_bf16(af[i], bfr[j], acc[i][j], 0, 0, 0);
  }
#pragma unroll
  for (int i = 0; i < 4; i++)
#pragma unroll
    for (int j = 0; j < 2; j++)
#pragma unroll
      for (int r = 0; r < 4; r++) {
        int n = nt * 128 + wm + i * 16 + quad * 4 + r;
        int dd = wn + j * 16 + l16;
        attn[((long)b * 4096 + n) * 768 + h * 64 + dd] = f2bf(acc[i][j][r]);
      }
}

// ---------------- K8: out = attn @ Wproj + bias, 128x256 BK32 core ----------------
__global__ __launch_bounds__(512, 4) void k_gemm_proj128(const unsigned short* __restrict__ attn,
                                                         const unsigned short* __restrict__ wprojT,
                                                         const float* __restrict__ bias,
                                                         float* __restrict__ out) {
  __shared__ __align__(16) unsigned short smem[24576];
  f32x4 acc[4][4];
  const int L = blockIdx.x;
  const int xcd = L & 7, slot = L >> 3;          // 96 slots per XCD
  const int rt = xcd * 32 + slot / 3;
  const int ct = slot % 3;
  gemm_bk32_core<24>(attn + (long)rt * 128 * 768, wprojT + (long)ct * 256 * 768, 768, acc, smem);
  const int tid = threadIdx.x, lane = tid & 63, wave = tid >> 6;
  const int l16 = lane & 15, quad = lane >> 4;
  const int wr = wave >> 2, wc = wave & 3;
  const long row0 = (long)rt * 128 + wr * 64;
#pragma unroll
  for (int m = 0; m < 4; m++)
#pragma unroll
    for (int n = 0; n < 4; n++) {
      int col = ct * 256 + wc * 64 + n * 16 + l16;
      float bv = bias[col];
#pragma unroll
      for (int r = 0; r < 4; r++) {
        long row = row0 + m * 16 + quad * 4 + r;
        out[row * 768 + col] = acc[m][n][r] + bv;
      }
    }
}

extern "C" void kernel_launch(void* const* d_in, const int* in_sizes, int n_in,
                              void* d_out, int out_size, void* d_ws, size_t ws_size,
                              hipStream_t stream) {
  const float* x = (const float*)d_in[0];
  const float* Wqkv = (const float*)d_in[1];
  const float* Wproj = (const float*)d_in[2];
  const float* bproj = (const float*)d_in[3];
  const float* rm = (const float*)d_in[4];
  float* out = (float*)d_out;

  size_t o = 0;
  char* wsb = (char*)d_ws;
  auto take = [&](size_t b) { char* p = wsb + o; o += b; return p; };
  unsigned short* wqkvT = (unsigned short*)take(2359296);
  unsigned short* wprojT = (unsigned short*)take(1179648);
  unsigned short* rmT = (unsigned short*)take(196608);
  unsigned short* q = (unsigned short*)take(50331648);    // reused: kkp, then attn
  unsigned short* vT = (unsigned short*)take(50331648);   // reused: kkred|kvred after kkkv
  float* colss = (float*)take(49152);
  unsigned short* sT = (unsigned short*)take(1572864);
  if (ws_size < o) return;

  unsigned short* xbf = (unsigned short*)d_out;  // dead before qnT claims d_out
  unsigned short* qnT = (unsigned short*)d_out;  // dead before K8
  unsigned short* kkp = q;                       // alias: q dead after rf
  unsigned short* attnbf = q;                    // alias: kkp dead after k_red
  unsigned short* kkred = vT;                    // alias: vT dead after kkkv
  float* kvred = (float*)(vT + 1572864);

  hipMemsetAsync(colss, 0, 49152, stream);

  k_convert_bf16<<<24576, 256, 0, stream>>>(x, xbf, 6291456L);
  k_transpose_tiled<<<dim3(48, 24, 1), 256, 0, stream>>>(Wqkv, wqkvT, 768, 1536, 1.0f);
  k_transpose_tiled<<<dim3(24, 24, 1), 256, 0, stream>>>(Wproj, wprojT, 768, 768, 1.0f);
  k_transpose_tiled<<<dim3(4, 2, 12), 256, 0, stream>>>(rm, rmT, 64, 128, 0.3535533905932738f);
  k_gemm_qkv128<<<1536, 512, 0, stream>>>(xbf, wqkvT, q, vT);
  k_gemm_rf<<<dim3(32, 96), 256, 0, stream>>>(q, rmT, qnT, colss);
  k_gemm_kkkv<<<dim3(8, 96), 256, 0, stream>>>(qnT, vT, colss, kkp);
  k_red<<<dim3(4, 96), 256, 0, stream>>>(kkp, kkred, kvred);
  k_ista2<<<96, 256, 0, stream>>>(kkred, kvred, colss, sT);
  k_gemm_attn<<<dim3(32, 96), 256, 0, stream>>>(qnT, sT, attnbf);
  k_gemm_proj128<<<768, 512, 0, stream>>>(attnbf, wprojT, bproj, out);
}

// Round 9
// 441.674 us; speedup vs baseline: 1.0395x; 1.0395x over previous
//
#include <hip/hip_runtime.h>

// ---------------------------------------------------------------------------
// VARS_D: fused linear-attention block on gfx950. Round 13.
//  - Consolidation on best-measured config (r11 = 450.5us):
//    qkv = 256^2 4-mega-phase core; proj = 128x256 BK64 core (768 = 3 rounds).
//    r12's qkv128/projBK32 reverted (occupancy theory falsified: 2x occupancy,
//    identical duration -> shape-bound plateau ~870 TF; qkv settled).
//  - k_pre: ONE launch fuses convert + 3 transposes + colss zeroing
//    (was 5 launches + memset; saves ~4 launch gaps).
//  - k_ista2: split into 2 d-halves per bh (192 blocks, 75% chip vs 37%);
//    L recomputed identically per block -> bit-identical numerics.
// ---------------------------------------------------------------------------

typedef __attribute__((ext_vector_type(8))) short bf16x8;
typedef __attribute__((ext_vector_type(4))) float f32x4;

#define GLD16(gptr, lptr)                                                              \
  __builtin_amdgcn_global_load_lds((const __attribute__((address_space(1))) void*)(gptr), \
                                   (__attribute__((address_space(3))) void*)(lptr), 16, 0, 0)

__device__ __forceinline__ unsigned short f2bf(float f) {
  union { float f; unsigned int u; } v; v.f = f;
  unsigned int r = v.u + 0x7fffu + ((v.u >> 16) & 1u);   // RNE
  return (unsigned short)(r >> 16);
}
__device__ __forceinline__ float bf2f(unsigned short s) {
  union { unsigned int u; float f; } v; v.u = ((unsigned int)s) << 16;
  return v.f;
}
__device__ __forceinline__ float rn_of(float css) {
  return 1.f / fmaxf(sqrtf(css), 1e-12f);
}

// ---------------------------------------------------------------------------
// 256x256 NT GEMM core (r7 4-mega-phase; best measured for qkv: 86.6-87.5us).
// See r7 notes for the staging WAR/FIFO proof.
// ---------------------------------------------------------------------------
template<int ITERS>
__device__ __forceinline__ void gemm256_core(
    const unsigned short* __restrict__ A,
    const unsigned short* __restrict__ B,
    int ldk,
    f32x4 (&acc)[8][4],
    unsigned short* smem) {
  const int tid = threadIdx.x;
  const int lane = tid & 63, wave = tid >> 6;
  const int l16 = lane & 15, quad = lane >> 4;
  const int wr = wave >> 2, wc = wave & 3;
  const int rsw = l16 & 7;

#pragma unroll
  for (int i = 0; i < 8; i++)
#pragma unroll
    for (int j = 0; j < 4; j++)
#pragma unroll
      for (int r = 0; r < 4; r++) acc[i][j][r] = 0.f;

  const int srow0 = tid >> 3, sc0 = ((tid & 7) ^ (srow0 & 7)) << 3;
  const int srow1 = (tid + 512) >> 3, sc1 = ((tid & 7) ^ (srow1 & 7)) << 3;
  const int dstw = wave * 512;  // wave-uniform lds chunk base (shorts)

  auto stageA = [&](int T, int h) {
    const unsigned short* g = A + (long)(h * 128) * ldk + T * 64;
    unsigned short* d = smem + (T & 1) * 32768 + h * 8192 + dstw;
    GLD16(g + (long)srow0 * ldk + sc0, d);
    GLD16(g + (long)srow1 * ldk + sc1, d + 4096);
  };
  auto stageB = [&](int T, int h) {
    const unsigned short* g = B + (long)(h * 128) * ldk + T * 64;
    unsigned short* d = smem + (T & 1) * 32768 + 16384 + h * 8192 + dstw;
    GLD16(g + (long)srow0 * ldk + sc0, d);
    GLD16(g + (long)srow1 * ldk + sc1, d + 4096);
  };

  bf16x8 af[4][2], bn[4][2];

  auto rdA_ks = [&](int b, int mh, int ks) {
    const unsigned short* p = smem + b * 32768 + wr * 8192 + (mh * 64 + l16) * 64;
#pragma unroll
    for (int ii = 0; ii < 4; ii++)
      af[ii][ks] = *(const bf16x8*)(p + ii * 1024 + (((ks * 4 + quad) ^ rsw) << 3));
  };
  auto rdB_ks = [&](int b, int ks) {
    const unsigned short* p = smem + b * 32768 + 16384 + (wc >> 1) * 8192 +
                              ((wc & 1) * 64 + l16) * 64;
#pragma unroll
    for (int jj = 0; jj < 4; jj++)
      bn[jj][ks] = *(const bf16x8*)(p + jj * 1024 + (((ks * 4 + quad) ^ rsw) << 3));
  };

  auto mma16 = [&](int mh, int ks) {
    __builtin_amdgcn_s_setprio(1);
#pragma unroll
    for (int ii = 0; ii < 4; ii++)
#pragma unroll
      for (int jj = 0; jj < 4; jj++)
        acc[mh * 4 + ii][jj] = __builtin_amdgcn_mfma_f32_16x16x32_bf16(
            af[ii][ks], bn[jj][ks], acc[mh * 4 + ii][jj], 0, 0, 0);
    __builtin_amdgcn_s_setprio(0);
  };

#define FENCE asm volatile("" ::: "memory")
#define SGB __builtin_amdgcn_sched_barrier(0)
#define LGKM(n) asm volatile("s_waitcnt lgkmcnt(" #n ")" ::: "memory")

  stageA(0, 0); stageA(0, 1); stageB(0, 0); stageB(0, 1);
  stageB(1, 0); stageB(1, 1);
  asm volatile("s_waitcnt vmcnt(4)" ::: "memory");
  __builtin_amdgcn_s_barrier();

#pragma unroll 1
  for (int i = 0; i < ITERS; i++) {
    const int u = 2 * i;
    const bool more = (i + 1 < ITERS);
    // ---- M0
    stageA(u + 1, 0);
    rdB_ks(0, 0); rdA_ks(0, 0, 0);
    SGB;
    rdB_ks(0, 1); rdA_ks(0, 0, 1);
    FENCE; __builtin_amdgcn_s_barrier();
    LGKM(8); SGB;
    mma16(0, 0);
    LGKM(0); SGB;
    mma16(0, 1);
    FENCE; __builtin_amdgcn_s_barrier();
    // ---- M1
    stageA(u + 1, 1);
    if (more) stageB(u + 2, 0);
    rdA_ks(0, 1, 0);
    SGB;
    rdA_ks(0, 1, 1);
    FENCE; __builtin_amdgcn_s_barrier();
    LGKM(4); SGB;
    mma16(1, 0);
    LGKM(0); SGB;
    mma16(1, 1);
    if (more) { asm volatile("s_waitcnt vmcnt(2)" ::: "memory"); }
    else      { asm volatile("s_waitcnt vmcnt(0)" ::: "memory"); }
    FENCE; __builtin_amdgcn_s_barrier();
    // ---- M2
    if (more) { stageB(u + 2, 1); stageA(u + 2, 0); stageA(u + 2, 1); }
    rdB_ks(1, 0); rdA_ks(1, 0, 0);
    SGB;
    rdB_ks(1, 1); rdA_ks(1, 0, 1);
    FENCE; __builtin_amdgcn_s_barrier();
    LGKM(8); SGB;
    mma16(0, 0);
    LGKM(0); SGB;
    mma16(0, 1);
    FENCE; __builtin_amdgcn_s_barrier();
    // ---- M3
    if (more) { stageB(u + 3, 0); stageB(u + 3, 1); }
    rdA_ks(1, 1, 0);
    SGB;
    rdA_ks(1, 1, 1);
    FENCE; __builtin_amdgcn_s_barrier();
    LGKM(4); SGB;
    mma16(1, 0);
    LGKM(0); SGB;
    mma16(1, 1);
    if (more) { asm volatile("s_waitcnt vmcnt(4)" ::: "memory"); }
    FENCE; __builtin_amdgcn_s_barrier();
  }
#undef FENCE
#undef SGB
#undef LGKM
}

// ---------------------------------------------------------------------------
// 128x256 NT GEMM core, BK=64 (r11 proj core; measured within the 450.5 total).
// ---------------------------------------------------------------------------
template<int NT>
__device__ __forceinline__ void gemm128x256_core(
    const unsigned short* __restrict__ A,   // 128 rows x ldk
    const unsigned short* __restrict__ B,   // 256 rows x ldk
    int ldk,
    f32x4 (&acc)[4][4],
    unsigned short* smem) {
  const int tid = threadIdx.x;
  const int lane = tid & 63, wave = tid >> 6;
  const int l16 = lane & 15, quad = lane >> 4;
  const int wr = wave >> 2, wc = wave & 3;
  const int rsw = l16 & 7;

#pragma unroll
  for (int m = 0; m < 4; m++)
#pragma unroll
    for (int n = 0; n < 4; n++)
#pragma unroll
      for (int r = 0; r < 4; r++) acc[m][n][r] = 0.f;

  const int srow0 = tid >> 3, sc0 = ((tid & 7) ^ (srow0 & 7)) << 3;
  const int srow1 = (tid + 512) >> 3, sc1 = ((tid & 7) ^ (srow1 & 7)) << 3;
  const int dstw = wave * 512;

  auto stage = [&](int T) {  // 6 loads/thread: A(2) + B(4)
    unsigned short* d = smem + (T & 1) * 24576;
    const unsigned short* gA = A + T * 64;
    const unsigned short* gB = B + T * 64;
    GLD16(gA + (long)srow0 * ldk + sc0, d + dstw);
    GLD16(gA + (long)srow1 * ldk + sc1, d + 4096 + dstw);
    GLD16(gB + (long)srow0 * ldk + sc0, d + 8192 + dstw);
    GLD16(gB + (long)srow1 * ldk + sc1, d + 8192 + 4096 + dstw);
    GLD16(gB + (long)(srow0 + 128) * ldk + sc0, d + 16384 + dstw);
    GLD16(gB + (long)(srow1 + 128) * ldk + sc1, d + 16384 + 4096 + dstw);
  };

  bf16x8 af[4][2], bn[4][2];

  auto rdA_ks = [&](int b, int ks) {
    const unsigned short* p = smem + b * 24576 + (wr * 64 + l16) * 64;
#pragma unroll
    for (int m = 0; m < 4; m++)
      af[m][ks] = *(const bf16x8*)(p + m * 1024 + (((ks * 4 + quad) ^ rsw) << 3));
  };
  auto rdB_ks = [&](int b, int ks) {
    const unsigned short* p = smem + b * 24576 + 8192 + (wc * 64 + l16) * 64;
#pragma unroll
    for (int n = 0; n < 4; n++)
      bn[n][ks] = *(const bf16x8*)(p + n * 1024 + (((ks * 4 + quad) ^ rsw) << 3));
  };

  auto mma16 = [&](int ks) {
    __builtin_amdgcn_s_setprio(1);
#pragma unroll
    for (int m = 0; m < 4; m++)
#pragma unroll
      for (int n = 0; n < 4; n++)
        acc[m][n] = __builtin_amdgcn_mfma_f32_16x16x32_bf16(
            af[m][ks], bn[n][ks], acc[m][n], 0, 0, 0);
    __builtin_amdgcn_s_setprio(0);
  };

#define FENCE asm volatile("" ::: "memory")
#define SGB __builtin_amdgcn_sched_barrier(0)
#define LGKM(n) asm volatile("s_waitcnt lgkmcnt(" #n ")" ::: "memory")

  stage(0); stage(1);
  asm volatile("s_waitcnt vmcnt(6)" ::: "memory");
  __builtin_amdgcn_s_barrier();

#pragma unroll 1
  for (int t = 0; t < NT; t++) {
    const int b = t & 1;
    rdA_ks(b, 0); rdB_ks(b, 0);
    SGB;
    rdA_ks(b, 1); rdB_ks(b, 1);
    LGKM(8); SGB;
    mma16(0);
    LGKM(0); SGB;
    mma16(1);
    FENCE; __builtin_amdgcn_s_barrier();
    if (t + 2 < NT) stage(t + 2);
    if (t + 1 < NT) {
      if (t + 2 < NT) { asm volatile("s_waitcnt vmcnt(6)" ::: "memory"); }
      else            { asm volatile("s_waitcnt vmcnt(0)" ::: "memory"); }
      FENCE; __builtin_amdgcn_s_barrier();
    }
  }
#undef FENCE
#undef SGB
#undef LGKM
}

// ---------------- K0: fused preprocessing (1 launch) ----------------
// blocks [0,24576): convert x fp32->bf16
// [24576,25728): Wqkv transpose (48x24)   [25728,26304): Wproj (24x24)
// [26304,26400): rm (4x2x12, scaled)      [26400,26448): zero colss
__global__ __launch_bounds__(256) void k_pre(const float* __restrict__ x,
                                             unsigned short* __restrict__ xbf,
                                             const float* __restrict__ Wqkv,
                                             unsigned short* __restrict__ wqkvT,
                                             const float* __restrict__ Wproj,
                                             unsigned short* __restrict__ wprojT,
                                             const float* __restrict__ rm,
                                             unsigned short* __restrict__ rmT,
                                             float* __restrict__ colss) {
  __shared__ float t[32][33];
  const int bid = blockIdx.x, tid = threadIdx.x;
  if (bid < 24576) {  // convert: 24576*256 float4 == 6291456 exactly
    long i = (long)bid * 256 + tid;
    float4 v = ((const float4*)x)[i];
    unsigned short o[4] = {f2bf(v.x), f2bf(v.y), f2bf(v.z), f2bf(v.w)};
    ((uint2*)xbf)[i] = *(uint2*)o;
    return;
  }
  int b2 = bid - 24576;
  const float* in; unsigned short* out; int R, C, c0, r0; float scale;
  if (b2 < 1152) {
    in = Wqkv; out = wqkvT; R = 768; C = 1536;
    c0 = (b2 % 48) * 32; r0 = (b2 / 48) * 32; scale = 1.f;
  } else if (b2 < 1152 + 576) {
    b2 -= 1152;
    in = Wproj; out = wprojT; R = 768; C = 768;
    c0 = (b2 % 24) * 32; r0 = (b2 / 24) * 32; scale = 1.f;
  } else if (b2 < 1152 + 576 + 96) {
    b2 -= 1152 + 576;
    int z = b2 / 8;
    in = rm + (long)z * 8192; out = rmT + (long)z * 8192;
    R = 64; C = 128;
    c0 = (b2 % 4) * 32; r0 = ((b2 / 4) & 1) * 32;
    scale = 0.3535533905932738f;  // fold qs = q * scale^0.5
  } else {
    b2 -= 1152 + 576 + 96;        // [0,48): zero colss (48*256 = 12288 floats)
    colss[b2 * 256 + tid] = 0.f;
    return;
  }
  int tx = tid & 31, ty = tid >> 5;
#pragma unroll
  for (int k = 0; k < 32; k += 8)
    t[ty + k][tx] = in[(long)(r0 + ty + k) * C + c0 + tx];
  __syncthreads();
#pragma unroll
  for (int k = 0; k < 32; k += 8)
    out[(long)(c0 + ty + k) * R + r0 + tx] = f2bf(t[tx][ty + k] * scale);
}

// ---------------- K1: qkv GEMM, 256^2 4-mega-phase core ----------------
__global__ __launch_bounds__(512, 2) void k_gemm_qkv256(const unsigned short* __restrict__ xbf,
                                                        const unsigned short* __restrict__ wqkvT,
                                                        unsigned short* __restrict__ q,
                                                        unsigned short* __restrict__ vT) {
  __shared__ __align__(16) unsigned short smem[65536];
  f32x4 acc[8][4];
  const int L = blockIdx.x;
  const int xcd = L & 7, slot = L >> 3;
  const int rt = xcd * 16 + slot / 6;
  const int ct = slot % 6;
  gemm256_core<6>(xbf + (long)rt * 256 * 768, wqkvT + (long)ct * 256 * 768, 768, acc, smem);

  const int tid = threadIdx.x, lane = tid & 63, wave = tid >> 6;
  const int l16 = lane & 15, quad = lane >> 4;
  const int wr = wave >> 2, wc = wave & 3;
  const int b = rt >> 4;
  const int nbase = (rt & 15) * 256;
  if (ct < 3) {  // pure-q columns -> q[bh][n][d]
#pragma unroll
    for (int i = 0; i < 8; i++)
#pragma unroll
      for (int j = 0; j < 4; j++) {
        int col = ct * 256 + wc * 64 + j * 16 + l16;
        int h = col >> 6, d = col & 63;
#pragma unroll
        for (int r = 0; r < 4; r++) {
          int n = nbase + wr * 128 + i * 16 + quad * 4 + r;
          q[((long)(b * 12 + h) * 4096 + n) * 64 + d] = f2bf(acc[i][j][r]);
        }
      }
  } else {  // pure-v columns: LDS transpose -> vT[bh][d][n]
    unsigned short* pool = smem;
    for (int hh = 0; hh < 2; hh++) {
      __syncthreads();
      if (wr == hh) {
#pragma unroll
        for (int i = 0; i < 8; i++)
#pragma unroll
          for (int j = 0; j < 4; j++)
#pragma unroll
            for (int r = 0; r < 4; r++)
              pool[(wc * 64 + j * 16 + l16) * 136 + i * 16 + quad * 4 + r] = f2bf(acc[i][j][r]);
      }
      __syncthreads();
#pragma unroll
      for (int it = 0; it < 8; it++) {
        int chunk = it * 512 + tid;
        int col = chunk >> 4, ng = chunk & 15;
        uint4 val = *(const uint4*)&pool[col * 136 + ng * 8];
        int vcol = (ct - 3) * 256 + col;
        int h = vcol >> 6, d = vcol & 63;
        long n = nbase + hh * 128 + ng * 8;
        *(uint4*)&vT[((long)(b * 12 + h) * 64 + d) * 4096 + n] = val;
      }
    }
  }
}

// ---------------- K3: rf GEMM, full-tile staged, halfnorm folded ----------------
__global__ __launch_bounds__(256) void k_gemm_rf(const unsigned short* __restrict__ q,
                                                 const unsigned short* __restrict__ rmT,
                                                 unsigned short* __restrict__ qnT,
                                                 float* __restrict__ colss) {
  __shared__ __align__(16) unsigned short smem[16384];
  __shared__ float hnp[256];
  __shared__ float css[128];
  unsigned short* Asm = smem;
  unsigned short* Bsm = smem + 8192;
  unsigned short* pool = smem;
  f32x4 acc[4][4];
  const int nt = blockIdx.x, bh = blockIdx.y, h = bh % 12;
  const int tid = threadIdx.x, lane = tid & 63, wave = tid >> 6;
  const int l16 = lane & 15, quad = lane >> 4;
  const int wm = (wave >> 1) * 64, wn = (wave & 1) * 64;
  const int fsw = (l16 >> 1) & 3;
  const unsigned short* Aq = q + ((long)bh * 4096 + nt * 128) * 64;
  const unsigned short* Brm = rmT + (long)h * 8192;

#pragma unroll
  for (int c = 0; c < 4; c++) {
    int chunk = c * 256 + tid;
    int row = chunk >> 3, ko8 = chunk & 7;
    int kc = ko8 >> 2;
    int c2s = (ko8 & 3) ^ ((row >> 1) & 3);
    *(uint4*)(Asm + kc * 4096 + row * 32 + c2s * 8) = *(const uint4*)(Aq + (long)row * 64 + ko8 * 8);
    *(uint4*)(Bsm + kc * 4096 + row * 32 + c2s * 8) = *(const uint4*)(Brm + (long)row * 64 + ko8 * 8);
  }
  for (int i = tid; i < 128; i += 256) css[i] = 0.f;
  __syncthreads();
  {
    const unsigned short* ap = Asm + (tid & 1) * 4096 + (tid >> 1) * 32;
    float ssum = 0.f;
#pragma unroll
    for (int e = 0; e < 32; e++) { float f = bf2f(ap[e]); ssum += f * f; }
    hnp[tid] = ssum;
  }
#pragma unroll
  for (int i = 0; i < 4; i++)
#pragma unroll
    for (int j = 0; j < 4; j++)
#pragma unroll
      for (int r = 0; r < 4; r++) acc[i][j][r] = 0.f;
#pragma unroll
  for (int kc = 0; kc < 2; kc++) {
    bf16x8 af[4], bfr[4];
#pragma unroll
    for (int i = 0; i < 4; i++)
      af[i] = *(const bf16x8*)(Asm + kc * 4096 + (wm + i * 16 + l16) * 32 + ((quad ^ fsw) * 8));
#pragma unroll
    for (int j = 0; j < 4; j++)
      bfr[j] = *(const bf16x8*)(Bsm + kc * 4096 + (wn + j * 16 + l16) * 32 + ((quad ^ fsw) * 8));
#pragma unroll
    for (int i = 0; i < 4; i++)
#pragma unroll
      for (int j = 0; j < 4; j++)
        acc[i][j] = __builtin_amdgcn_mfma_f32_16x16x32_bf16(af[i], bfr[j], acc[i][j], 0, 0, 0);
  }
  __syncthreads();
  float hnv[4][4];
#pragma unroll
  for (int i = 0; i < 4; i++)
#pragma unroll
    for (int r = 0; r < 4; r++) {
      int row = wm + i * 16 + quad * 4 + r;
      hnv[i][r] = 0.0625f * (hnp[2 * row] + hnp[2 * row + 1]);
    }
#pragma unroll
  for (int j = 0; j < 4; j++) {
    int col = wn + j * 16 + l16;
    float cp = 0.f;
#pragma unroll
    for (int i = 0; i < 4; i++)
#pragma unroll
      for (int r = 0; r < 4; r++) {
        float v = __expf(acc[i][j][r] - hnv[i][r]) * 0.08838834764831845f;
        acc[i][j][r] = v;
        cp += v * v;
      }
    atomicAdd(&css[col], cp);
  }
  __syncthreads();
  for (int i = tid; i < 128; i += 256) atomicAdd(&colss[bh * 128 + i], css[i]);
  for (int hh = 0; hh < 2; hh++) {
    __syncthreads();
    if ((wave >> 1) == hh) {
#pragma unroll
      for (int i = 0; i < 4; i++)
#pragma unroll
        for (int j = 0; j < 4; j++)
#pragma unroll
          for (int r = 0; r < 4; r++)
            pool[(i * 16 + quad * 4 + r) * 134 + wn + j * 16 + l16] = f2bf(acc[i][j][r]);
    }
    __syncthreads();
#pragma unroll
    for (int c = 0; c < 4; c++) {
      int chunk = tid + c * 256;
      int m = chunk >> 3, nj = (chunk & 7) * 8;
      unsigned short o[8];
#pragma unroll
      for (int e = 0; e < 8; e++) o[e] = pool[(nj + e) * 134 + m];
      *(uint4*)&qnT[((long)bh * 128 + m) * 4096 + nt * 128 + hh * 64 + nj] = *(uint4*)o;
    }
  }
}

// ---------------- K5: kk|kv NT GEMM, A-panel shared for B0 ----------------
__global__ __launch_bounds__(256) void k_gemm_kkkv(const unsigned short* __restrict__ qnT,
                                                   const unsigned short* __restrict__ vT,
                                                   const float* __restrict__ colss,
                                                   unsigned short* __restrict__ kkp) {
  __shared__ __align__(16) unsigned short As[128 * 32], Bs[64 * 32];
  f32x4 acc[4][6];
  const int ks = blockIdx.x, bh = blockIdx.y;
  const unsigned short* A = qnT + (long)bh * 128 * 4096 + ks * 512;
  const unsigned short* B1 = vT + (long)bh * 64 * 4096 + ks * 512;
  const int tid = threadIdx.x, lane = tid & 63, wave = tid >> 6;
  const int l16 = lane & 15, quad = lane >> 4;
  const int wm = (wave >> 1) * 64, wn = (wave & 1) * 96;
  const int arow = tid >> 2;
  const int akos = (((tid & 3) ^ ((arow >> 1) & 3)) << 3);
  const int fsw = (l16 >> 1) & 3;
#pragma unroll
  for (int i = 0; i < 4; i++)
#pragma unroll
    for (int j = 0; j < 6; j++)
#pragma unroll
      for (int r = 0; r < 4; r++) acc[i][j][r] = 0.f;
  for (int k0 = 0; k0 < 512; k0 += 32) {
    __syncthreads();
    GLD16(A + (long)arow * 4096 + k0 + akos, As + wave * 512);
    GLD16(A + (long)(arow + 64) * 4096 + k0 + akos, As + 2048 + wave * 512);
    GLD16(B1 + (long)arow * 4096 + k0 + akos, Bs + wave * 512);
    __syncthreads();
    bf16x8 af[4], bfr[6];
#pragma unroll
    for (int i = 0; i < 4; i++)
      af[i] = *(const bf16x8*)(As + (wm + i * 16 + l16) * 32 + ((quad ^ fsw) * 8));
#pragma unroll
    for (int j = 0; j < 6; j++) {
      int row = wn + j * 16 + l16;
      const unsigned short* rp = (row < 128) ? (As + row * 32) : (Bs + (row - 128) * 32);
      bfr[j] = *(const bf16x8*)(rp + ((quad ^ fsw) * 8));
    }
#pragma unroll
    for (int i = 0; i < 4; i++)
#pragma unroll
      for (int j = 0; j < 6; j++)
        acc[i][j] = __builtin_amdgcn_mfma_f32_16x16x32_bf16(af[i], bfr[j], acc[i][j], 0, 0, 0);
  }
  unsigned short* dst = kkp + ((long)ks * 96 + bh) * 24576;
  float rnr[4][4];
#pragma unroll
  for (int i = 0; i < 4; i++)
#pragma unroll
    for (int r = 0; r < 4; r++)
      rnr[i][r] = rn_of(colss[bh * 128 + wm + i * 16 + quad * 4 + r]);
#pragma unroll
  for (int j = 0; j < 6; j++) {
    int col = wn + j * 16 + l16;
    float rnc = (col < 128) ? rn_of(colss[bh * 128 + col]) : 1.f;
#pragma unroll
    for (int i = 0; i < 4; i++)
#pragma unroll
      for (int r = 0; r < 4; r++) {
        int row = wm + i * 16 + quad * 4 + r;
        dst[row * 192 + col] = f2bf(acc[i][j][r] * rnr[i][r] * rnc);
      }
  }
}

// ---------------- K5b: reduce kkp 8 K-partials (full-chip width) ----------------
__global__ __launch_bounds__(256) void k_red(const unsigned short* __restrict__ kkp,
                                             unsigned short* __restrict__ kkred,
                                             float* __restrict__ kvred) {
  const int g = blockIdx.x, bh = blockIdx.y;
  const int tid = threadIdx.x;
  const unsigned short* base = kkp + (long)bh * 24576 + (long)(g * 32) * 192;
#pragma unroll
  for (int c = 0; c < 3; c++) {
    int idx = c * 256 + tid;
    int m = idx / 24, c8 = idx % 24;
    float f[8] = {0.f, 0.f, 0.f, 0.f, 0.f, 0.f, 0.f, 0.f};
#pragma unroll
    for (int ks = 0; ks < 8; ks++) {
      union { uint4 u; unsigned short s[8]; } u;
      u.u = *(const uint4*)(base + (long)ks * 2359296 + m * 192 + c8 * 8);
#pragma unroll
      for (int e = 0; e < 8; e++) f[e] += bf2f(u.s[e]);
    }
    long row = (long)bh * 128 + g * 32 + m;
    if (c8 < 16) {
      unsigned short o[8];
#pragma unroll
      for (int e = 0; e < 8; e++) o[e] = f2bf(f[e]);
      *(uint4*)&kkred[row * 128 + c8 * 8] = *(uint4*)o;
    } else {
      *(float4*)&kvred[row * 64 + (c8 - 16) * 8] = make_float4(f[0], f[1], f[2], f[3]);
      *(float4*)&kvred[row * 64 + (c8 - 16) * 8 + 4] = make_float4(f[4], f[5], f[6], f[7]);
    }
  }
}

// ---------------- K6: ISTA via MFMA; split into 2 d-halves per bh ----------------
// blockIdx.x = bh*2 + dh. Each block handles s columns [dh*32, dh*32+32).
// L is recomputed from the full kk in both blocks -> bit-identical numerics.
__global__ __launch_bounds__(256) void k_ista2(const unsigned short* __restrict__ kkred,
                                               const float* __restrict__ kvred,
                                               const float* __restrict__ colss,
                                               unsigned short* __restrict__ sT) {
  __shared__ __align__(16) unsigned short kks[128 * 144];
  __shared__ __align__(16) unsigned short ssT[32 * 144];
  __shared__ float kvs[128 * 32];
  __shared__ float red[128];
  __shared__ float rns[128];
  const int tid = threadIdx.x, lane = tid & 63, wave = tid >> 6;
  const int l16 = lane & 15, quad = lane >> 4;
  const int wm = (wave >> 1) * 64, wn = (wave & 1) * 16;
  const int bh = blockIdx.x >> 1, d0 = (blockIdx.x & 1) * 32;
  for (int idx = tid; idx < 2048; idx += 256) {   // full kk
    int m = idx >> 4, c8 = idx & 15;
    uint4 v = *(const uint4*)(kkred + ((long)bh * 128 + m) * 128 + c8 * 8);
    *(uint4*)&kks[m * 144 + c8 * 8] = v;
  }
  for (int idx = tid; idx < 1024; idx += 256) {   // kv: own 32-d slice
    int m = idx >> 3, c4 = idx & 7;
    float4 v = *(const float4*)(kvred + ((long)bh * 128 + m) * 64 + d0 + c4 * 4);
    *(float4*)&kvs[m * 32 + c4 * 4] = v;
  }
  __syncthreads();
  float kv[4][4];
#pragma unroll
  for (int i = 0; i < 4; i++)
#pragma unroll
    for (int r = 0; r < 4; r++) {
      int m = wm + i * 16 + quad * 4 + r, dl = wn + l16;
      kv[i][r] = kvs[m * 32 + dl];
    }
  if (tid < 128) {   // full-row L1 norms (identical in both d-blocks) + rn
    float rs = 0.f;
    const unsigned short* rp = kks + tid * 144;
    for (int p = 0; p < 128; p++) rs += fabsf(bf2f(rp[p]));
    red[tid] = rs;
    rns[tid] = rn_of(colss[bh * 128 + tid]);
  }
  __syncthreads();
  for (int o = 64; o > 0; o >>= 1) {
    if (tid < o) red[tid] = fmaxf(red[tid], red[tid + o]);
    __syncthreads();
  }
  const float L = red[0] + 1.f;
  const float invL = 1.f / L;
  const float lamL = 0.3f * invL;
  float sreg[4][4];
#pragma unroll
  for (int i = 0; i < 4; i++)
#pragma unroll
    for (int r = 0; r < 4; r++) {
      float z = kv[i][r];
      float az = fabsf(z) - 0.3f;
      float s = az > 0.f ? copysignf(az, z) : 0.f;
      sreg[i][r] = s;
      ssT[(wn + l16) * 144 + wm + i * 16 + quad * 4 + r] = f2bf(s);
    }
  for (int step = 0; step < 5; step++) {
    __syncthreads();
    f32x4 acc[4];
#pragma unroll
    for (int i = 0; i < 4; i++)
#pragma unroll
      for (int r = 0; r < 4; r++) acc[i][r] = 0.f;
#pragma unroll
    for (int kc = 0; kc < 4; kc++) {
      bf16x8 af[4], bfj;
#pragma unroll
      for (int i = 0; i < 4; i++)
        af[i] = *(const bf16x8*)(kks + (wm + i * 16 + l16) * 144 + kc * 32 + quad * 8);
      bfj = *(const bf16x8*)(ssT + (wn + l16) * 144 + kc * 32 + quad * 8);
#pragma unroll
      for (int i = 0; i < 4; i++)
        acc[i] = __builtin_amdgcn_mfma_f32_16x16x32_bf16(af[i], bfj, acc[i], 0, 0, 0);
    }
    __syncthreads();
#pragma unroll
    for (int i = 0; i < 4; i++)
#pragma unroll
      for (int r = 0; r < 4; r++) {
        float z = sreg[i][r] - (acc[i][r] - kv[i][r]) * invL;
        float az = fabsf(z) - lamL;
        float s = az > 0.f ? copysignf(az, z) : 0.f;
        sreg[i][r] = s;
        ssT[(wn + l16) * 144 + wm + i * 16 + quad * 4 + r] = f2bf(s);
      }
  }
#pragma unroll
  for (int i = 0; i < 4; i++)
#pragma unroll
    for (int r = 0; r < 4; r++) {
      int m = wm + i * 16 + quad * 4 + r, d = d0 + wn + l16;
      sT[(long)bh * 8192 + d * 128 + m] = f2bf(sreg[i][r] * rns[m]);
    }
}

// ---------------- K7: attn = qn @ s; permuted As2 (conflict-free gather) ----------------
__global__ __launch_bounds__(256) void k_gemm_attn(const unsigned short* __restrict__ qnT,
                                                   const unsigned short* __restrict__ sT,
                                                   unsigned short* __restrict__ attn) {
  __shared__ __align__(16) unsigned short As2[4352];
  __shared__ __align__(16) unsigned short Bs[64 * 32];
  f32x4 acc[4][2];
  const int nt = blockIdx.x, bh = blockIdx.y;
  const int b = bh / 12, h = bh % 12;
  const int tid = threadIdx.x, lane = tid & 63, wave = tid >> 6;
  const int l16 = lane & 15, quad = lane >> 4;
  const int wm = (wave >> 1) * 64, wn = (wave & 1) * 32;
  const int fsw = (l16 >> 1) & 3;
#pragma unroll
  for (int i = 0; i < 4; i++)
#pragma unroll
    for (int j = 0; j < 2; j++)
#pragma unroll
      for (int r = 0; r < 4; r++) acc[i][j][r] = 0.f;
  for (int k0 = 0; k0 < 128; k0 += 32) {
    __syncthreads();
#pragma unroll
    for (int it = 0; it < 3; it++) {
      if (it < 2 || tid < 32) {
        int c = it * 256 + tid;
        int p = (c * 241) >> 12;
        int nh = c - p * 17;
        int k = ((p & 7) << 2) + (p >> 3);
        int n8 = (nh < 16 ? nh : 15) << 3;
        const unsigned short* gp = qnT + ((long)bh * 128 + k0 + k) * 4096 + nt * 128 + n8;
        GLD16(gp, As2 + (it * 256 + wave * 64) * 8);
      }
    }
    {
      int dd = tid >> 2;
      int ko = (((tid & 3) ^ ((dd >> 1) & 3)) * 8);
      const unsigned short* gp = sT + ((long)bh * 64 + dd) * 128 + k0 + ko;
      GLD16(gp, Bs + wave * 512);
    }
    __syncthreads();
    bf16x8 af[4], bfr[2];
#pragma unroll
    for (int i = 0; i < 4; i++) {
      union { bf16x8 v; unsigned short s[8]; } u;
#pragma unroll
      for (int e = 0; e < 8; e++) {
        int p = ((e & 3) << 3) + (quad << 1) + (e >> 2);
        u.s[e] = As2[p * 136 + wm + i * 16 + l16];
      }
      af[i] = u.v;
    }
#pragma unroll
    for (int j = 0; j < 2; j++)
      bfr[j] = *(const bf16x8*)&Bs[(wn + j * 16 + l16) * 32 + ((quad ^ fsw) * 8)];
#pragma unroll
    for (int i = 0; i < 4; i++)
#pragma unroll
      for (int j = 0; j < 2; j++)
        acc[i][j] = __builtin_amdgcn_mfma_f32_16x16x32_bf16(af[i], bfr[j], acc[i][j], 0, 0, 0);
  }
#pragma unroll
  for (int i = 0; i < 4; i++)
#pragma unroll
    for (int j = 0; j < 2; j++)
#pragma unroll
      for (int r = 0; r < 4; r++) {
        int n = nt * 128 + wm + i * 16 + quad * 4 + r;
        int dd = wn + j * 16 + l16;
        attn[((long)b * 4096 + n) * 768 + h * 64 + dd] = f2bf(acc[i][j][r]);
      }
}

// ---------------- K8: out = attn @ Wproj + bias, 128x256 BK64 core ----------------
__global__ __launch_bounds__(512, 2) void k_gemm_proj128(const unsigned short* __restrict__ attn,
                                                         const unsigned short* __restrict__ wprojT,
                                                         const float* __restrict__ bias,
                                                         float* __restrict__ out) {
  __shared__ __align__(16) unsigned short smem[49152];
  f32x4 acc[4][4];
  const int L = blockIdx.x;
  const int xcd = L & 7, slot = L >> 3;
  const int rt = xcd * 32 + slot / 3;
  const int ct = slot % 3;
  gemm128x256_core<12>(attn + (long)rt * 128 * 768, wprojT + (long)ct * 256 * 768, 768,
                       acc, smem);
  const int tid = threadIdx.x, lane = tid & 63, wave = tid >> 6;
  const int l16 = lane & 15, quad = lane >> 4;
  const int wr = wave >> 2, wc = wave & 3;
  const long row0 = (long)rt * 128 + wr * 64;
#pragma unroll
  for (int m = 0; m < 4; m++)
#pragma unroll
    for (int n = 0; n < 4; n++) {
      int col = ct * 256 + wc * 64 + n * 16 + l16;
      float bv = bias[col];
#pragma unroll
      for (int r = 0; r < 4; r++) {
        long row = row0 + m * 16 + quad * 4 + r;
        out[row * 768 + col] = acc[m][n][r] + bv;
      }
    }
}

extern "C" void kernel_launch(void* const* d_in, const int* in_sizes, int n_in,
                              void* d_out, int out_size, void* d_ws, size_t ws_size,
                              hipStream_t stream) {
  const float* x = (const float*)d_in[0];
  const float* Wqkv = (const float*)d_in[1];
  const float* Wproj = (const float*)d_in[2];
  const float* bproj = (const float*)d_in[3];
  const float* rm = (const float*)d_in[4];
  float* out = (float*)d_out;

  size_t o = 0;
  char* wsb = (char*)d_ws;
  auto take = [&](size_t b) { char* p = wsb + o; o += b; return p; };
  unsigned short* wqkvT = (unsigned short*)take(2359296);
  unsigned short* wprojT = (unsigned short*)take(1179648);
  unsigned short* rmT = (unsigned short*)take(196608);
  unsigned short* q = (unsigned short*)take(50331648);    // reused: kkp, then attn
  unsigned short* vT = (unsigned short*)take(50331648);   // reused: kkred|kvred after kkkv
  float* colss = (float*)take(49152);
  unsigned short* sT = (unsigned short*)take(1572864);
  if (ws_size < o) return;

  unsigned short* xbf = (unsigned short*)d_out;  // dead before qnT claims d_out
  unsigned short* qnT = (unsigned short*)d_out;  // dead before K8
  unsigned short* kkp = q;                       // alias: q dead after rf
  unsigned short* attnbf = q;                    // alias: kkp dead after k_red
  unsigned short* kkred = vT;                    // alias: vT dead after kkkv
  float* kvred = (float*)(vT + 1572864);

  k_pre<<<26448, 256, 0, stream>>>(x, xbf, Wqkv, wqkvT, Wproj, wprojT, rm, rmT, colss);
  k_gemm_qkv256<<<768, 512, 0, stream>>>(xbf, wqkvT, q, vT);
  k_gemm_rf<<<dim3(32, 96), 256, 0, stream>>>(q, rmT, qnT, colss);
  k_gemm_kkkv<<<dim3(8, 96), 256, 0, stream>>>(qnT, vT, colss, kkp);
  k_red<<<dim3(4, 96), 256, 0, stream>>>(kkp, kkred, kvred);
  k_ista2<<<192, 256, 0, stream>>>(kkred, kvred, colss, sT);
  k_gemm_attn<<<dim3(32, 96), 256, 0, stream>>>(qnT, sT, attnbf);
  k_gemm_proj128<<<768, 512, 0, stream>>>(attnbf, wprojT, bproj, out);
}